// Round 4
// baseline (6690.198 us; speedup 1.0000x reference)
//
#include <hip/hip_runtime.h>
#include <hip/hip_bf16.h>
#include <stdint.h>

// Problem constants
#define NB 128    // batch
#define NT 512    // time steps
#define ND 256    // input dim
#define NH 1024   // hidden dim
#define NZ 128    // latent dim
#define NG 4096   // 4*NH gate width
#define NK 1280   // ND + NH combined K

typedef __attribute__((ext_vector_type(8))) __bf16 bf16x8;
typedef __attribute__((ext_vector_type(4))) __bf16 bf16x4;
typedef __attribute__((ext_vector_type(4))) float floatx4;

__device__ __forceinline__ float sigmoidf_(float x) { return 1.0f / (1.0f + expf(-x)); }
__device__ __forceinline__ float softplusf_(float x) {
  return (x > 0.0f) ? (x + log1pf(expf(-x))) : log1pf(expf(x));
}

// ---------------------------------------------------------------------------
// Kernel 1: convert x (B,T,D) fp32 -> xb (T,B,D) bf16
// ---------------------------------------------------------------------------
__global__ __launch_bounds__(256) void convert_x_kernel(
    const float4* __restrict__ x, __bf16* __restrict__ xb) {
  int i = blockIdx.x * 256 + threadIdx.x;   // [0, B*T*D/4)
  int d4 = i & 63;                          // float4 index within row of 256
  int bt = i >> 6;                          // b*512 + t
  int b = bt >> 9;
  int t = bt & 511;
  float4 v = x[i];
  bf16x4 o;
  o[0] = (__bf16)v.x; o[1] = (__bf16)v.y; o[2] = (__bf16)v.z; o[3] = (__bf16)v.w;
  *(bf16x4*)(xb + ((t * NB + b) * ND + d4 * 4)) = o;
}

// ---------------------------------------------------------------------------
// Kernel 2: persistent LSTM.
// Grid 256 WGs x 512 thr (1 WG/CU, cooperative).
//   m_blk = wg & 3   -> batch rows [m_blk*32, +32)
//   n_blk = wg >> 2  -> h-cols    [n_blk*16, +16)
// Wave w: gate g = w&3 (i,f,g,o), K-half kh = w>>2 ([kh*640, +640)).
// Each wave holds 20 B-fragments (80 VGPRs) as NAMED variables (B0..B19) so
// the register allocator cannot demote them to scratch (round-2 failure mode:
// Bf[40] array spilled, VGPR_Count=116, 84 MB/step scratch reloads).
// The two K-half partials are reduced through LDS (Gs[2]).
// Cross-WG h exchange + slot barrier: agent-scope atomics only (no fences).
// ROUND-3 BUG FIX: h staging is 32 rows x 256 8B-chunks = 8192 chunks ->
// it<16, hr=idx>>8, hc=idx&255 (was it<8/hc&127: half of every row unstaged
// -> NaN from uninitialized LDS).
// ---------------------------------------------------------------------------
__global__ __launch_bounds__(512, 2) void lstm_persistent(
    const __bf16* __restrict__ xb,    // (T, B, D) bf16
    const float* __restrict__ W,      // (D, 4H)
    const float* __restrict__ U,      // (H, 4H)
    const float* __restrict__ bias,   // (4H)
    __bf16* __restrict__ hbuf,        // 2 * B * H bf16 (double buffer)
    float* __restrict__ hlast,        // B * H fp32
    unsigned int* __restrict__ slots) // 256 barrier slots (4 groups x 64)
{
  const int tid = threadIdx.x;
  const int wg = blockIdx.x;
  const int m_blk = wg & 3;
  const int n_blk = wg >> 2;
  const int wave = tid >> 6;
  const int lane = tid & 63;
  const int q = lane >> 4;     // k-quad
  const int n16 = lane & 15;   // MFMA col within 16-col tile
  const int g = wave & 3;      // gate index 0..3 (i,f,g,o)
  const int kh = wave >> 2;    // K-half 0/1

  __shared__ __bf16 As[32 * 1288];  // A tile, rows padded 1280 -> 1288
  __shared__ float Gs[2][32][68];   // per-K-half gate partials, 64+4 pad
  __shared__ __bf16 Hso[32][16];    // h output tile

  // ---- Load persistent B fragments as 20 named bf16x8 (80 VGPRs) ----
  const int gc = g * NH + n_blk * 16 + n16;  // global gate column
#define LB(ii)                                                            \
  bf16x8 B##ii;                                                           \
  {                                                                       \
    const int k0 = kh * 640 + (ii) * 32;                                  \
    const float* s = (k0 < 256) ? (W + k0 * NG + gc)                      \
                                : (U + (k0 - 256) * NG + gc);             \
    bf16x8 v;                                                             \
    v[0] = (__bf16)s[(q * 8 + 0) * NG]; v[1] = (__bf16)s[(q * 8 + 1) * NG]; \
    v[2] = (__bf16)s[(q * 8 + 2) * NG]; v[3] = (__bf16)s[(q * 8 + 3) * NG]; \
    v[4] = (__bf16)s[(q * 8 + 4) * NG]; v[5] = (__bf16)s[(q * 8 + 5) * NG]; \
    v[6] = (__bf16)s[(q * 8 + 6) * NG]; v[7] = (__bf16)s[(q * 8 + 7) * NG]; \
    B##ii = v;                                                            \
  }
  LB(0) LB(1) LB(2) LB(3) LB(4) LB(5) LB(6) LB(7) LB(8) LB(9)
  LB(10) LB(11) LB(12) LB(13) LB(14) LB(15) LB(16) LB(17) LB(18) LB(19)
#undef LB

  // ---- Elementwise-role constants: thread owns cell (r_e, c_e) ----
  const int r_e = tid >> 4;            // 0..31 row
  const int c_e = tid & 15;            // 0..15 h-col
  const int hcol = n_blk * 16 + c_e;   // [0, NH)
  const int grow = m_blk * 32 + r_e;   // [0, NB)
  const float bi = bias[hcol];
  const float bf = bias[NH + hcol];
  const float bg = bias[2 * NH + hcol];
  const float bo = bias[3 * NH + hcol];
  float c_state = 0.0f;

  const int slot_base = m_blk * 64;

  // ---- Initial staging for t=0: x(0) + h(0) (h is zeroed by host) ----
  {
#pragma unroll
    for (int it = 0; it < 2; ++it) {
      int idx = tid + it * 512;        // 1024 chunks of 16B (x)
      int r = idx >> 5, c = idx & 31;
      bf16x8 xv = ((const bf16x8*)(xb + (m_blk * 32 + r) * ND))[c];
      *(bf16x8*)(As + r * 1288 + c * 8) = xv;
    }
    const __bf16* hsrc = hbuf;         // t=0 reads buffer 0
#pragma unroll
    for (int it = 0; it < 16; ++it) {
      int idx = tid + it * 512;        // 8192 chunks of 8B (h: 32 x 256)
      int hr = idx >> 8, hc = idx & 255;
      unsigned long long v = __hip_atomic_load(
          (const unsigned long long*)(hsrc + (m_blk * 32 + hr) * NH) + hc,
          __ATOMIC_RELAXED, __HIP_MEMORY_SCOPE_AGENT);
      *(unsigned long long*)(As + hr * 1288 + 256 + hc * 4) = v;
    }
  }

  for (int t = 0; t < NT; ++t) {
    __syncthreads();  // staged A visible

    // ---- MFMA: 2 m-subtiles x 20 k-frags, 4 independent chains ----
    floatx4 accA0 = {0.f, 0.f, 0.f, 0.f}, accA1 = {0.f, 0.f, 0.f, 0.f};
    floatx4 accB0 = {0.f, 0.f, 0.f, 0.f}, accB1 = {0.f, 0.f, 0.f, 0.f};
    const __bf16* arow0 = As + n16 * 1288 + kh * 640 + q * 8;
    const __bf16* arow1 = arow0 + 16 * 1288;
#define MF(ii, ACC0, ACC1)                                                 \
  {                                                                        \
    bf16x8 a0 = *(const bf16x8*)(arow0 + (ii) * 32);                       \
    bf16x8 a1 = *(const bf16x8*)(arow1 + (ii) * 32);                       \
    ACC0 = __builtin_amdgcn_mfma_f32_16x16x32_bf16(a0, B##ii, ACC0, 0, 0, 0); \
    ACC1 = __builtin_amdgcn_mfma_f32_16x16x32_bf16(a1, B##ii, ACC1, 0, 0, 0); \
  }
    MF(0, accA0, accB0) MF(1, accA1, accB1)
    MF(2, accA0, accB0) MF(3, accA1, accB1)
    MF(4, accA0, accB0) MF(5, accA1, accB1)
    MF(6, accA0, accB0) MF(7, accA1, accB1)
    MF(8, accA0, accB0) MF(9, accA1, accB1)
    MF(10, accA0, accB0) MF(11, accA1, accB1)
    MF(12, accA0, accB0) MF(13, accA1, accB1)
    MF(14, accA0, accB0) MF(15, accA1, accB1)
    MF(16, accA0, accB0) MF(17, accA1, accB1)
    MF(18, accA0, accB0) MF(19, accA1, accB1)
#undef MF
    floatx4 accA = accA0 + accA1;  // rows q*4..+4
    floatx4 accB = accB0 + accB1;  // rows 16+q*4..+4

    // ---- Spill partial gate tiles: Gs[kh][m][g*16+n16] ----
#pragma unroll
    for (int rr = 0; rr < 4; ++rr) {
      Gs[kh][q * 4 + rr][g * 16 + n16] = accA[rr];
      Gs[kh][16 + q * 4 + rr][g * 16 + n16] = accB[rr];
    }
    __syncthreads();  // gates ready (As also fully consumed)

    // ---- LSTM cell (fp32): sum K-halves, add bias ----
    {
      float xi = Gs[0][r_e][c_e] + Gs[1][r_e][c_e] + bi;
      float xf = Gs[0][r_e][16 + c_e] + Gs[1][r_e][16 + c_e] + bf;
      float xg = Gs[0][r_e][32 + c_e] + Gs[1][r_e][32 + c_e] + bg;
      float xo = Gs[0][r_e][48 + c_e] + Gs[1][r_e][48 + c_e] + bo;
      float iv = sigmoidf_(xi);
      float fv = sigmoidf_(xf);
      float gv = softplusf_(xg);
      float ov = sigmoidf_(xo);
      c_state = fv * c_state + iv * gv;
      float hv = ov * softplusf_(c_state);
      Hso[r_e][c_e] = (__bf16)hv;
      if (t == NT - 1) hlast[grow * NH + hcol] = hv;
    }
    __syncthreads();  // Hso ready, Gs consumed

    if (t < NT - 1) {
      // ---- Prefetch next x tile into registers (h-independent) ----
      bf16x8 xv0, xv1;
      {
        int idx0 = tid, idx1 = tid + 512;
        xv0 = ((const bf16x8*)(xb + ((t + 1) * NB + m_blk * 32 + (idx0 >> 5)) * ND))[idx0 & 31];
        xv1 = ((const bf16x8*)(xb + ((t + 1) * NB + m_blk * 32 + (idx1 >> 5)) * ND))[idx1 & 31];
      }
      // ---- wave 0: publish h tile (32x16 bf16 = 128 x 8B, agent scope) ----
      if (tid < 64) {
        __bf16* hdst = hbuf + ((t + 1) & 1) * (NB * NH);
#pragma unroll
        for (int it = 0; it < 2; ++it) {
          int idx = tid + it * 64;          // 128 chunks of 8B
          int hr = idx >> 2, hc = idx & 3;  // row, 8B-chunk (16 cols = 4)
          unsigned long long v = *(const unsigned long long*)(&Hso[hr][hc * 4]);
          __hip_atomic_store(
              (unsigned long long*)(hdst + (m_blk * 32 + hr) * NH + n_blk * 16) + hc,
              v, __ATOMIC_RELAXED, __HIP_MEMORY_SCOPE_AGENT);
        }
      }
      if (tid == 0) {
        // release: same-wave h stores drain (vmcnt) before slot publish
        __hip_atomic_store(&slots[slot_base + n_blk], (unsigned)(t + 1),
                           __ATOMIC_RELEASE, __HIP_MEMORY_SCOPE_AGENT);
      }
      if (tid < 64) {  // wave 0 polls all 64 group slots
        unsigned tgt = (unsigned)(t + 1);
        while (__hip_atomic_load(&slots[slot_base + tid], __ATOMIC_RELAXED,
                                 __HIP_MEMORY_SCOPE_AGENT) < tgt) {
          __builtin_amdgcn_s_sleep(1);
        }
      }
      __syncthreads();  // all waves wait for barrier

      // ---- Stage A for t+1: x from regs, h from LLC ----
      {
        int r0 = tid >> 5, c0 = tid & 31;
        *(bf16x8*)(As + r0 * 1288 + c0 * 8) = xv0;
        int idx1 = tid + 512;
        *(bf16x8*)(As + (idx1 >> 5) * 1288 + (idx1 & 31) * 8) = xv1;
        const __bf16* hsrc = hbuf + ((t + 1) & 1) * (NB * NH);
#pragma unroll
        for (int it = 0; it < 16; ++it) {
          int idx = tid + it * 512;      // 8192 chunks of 8B (h: 32 x 256)
          int hr = idx >> 8, hc = idx & 255;
          unsigned long long v = __hip_atomic_load(
              (const unsigned long long*)(hsrc + (m_blk * 32 + hr) * NH) + hc,
              __ATOMIC_RELAXED, __HIP_MEMORY_SCOPE_AGENT);
          *(unsigned long long*)(As + hr * 1288 + 256 + hc * 4) = v;
        }
      }
    }
  }
}

// ---------------------------------------------------------------------------
// Kernel 3: projection head. 32 blocks x 128 thr; 4 batch rows per block.
// ---------------------------------------------------------------------------
__global__ __launch_bounds__(128) void proj_kernel(
    const float* __restrict__ hlast,
    const float* __restrict__ Wm, const float* __restrict__ bm,
    const float* __restrict__ Wv, const float* __restrict__ bv,
    const float* __restrict__ eps, float* __restrict__ out) {
  __shared__ float hs[4][NH];
  const int bb = blockIdx.x * 4;
  for (int idx = threadIdx.x; idx < 4 * NH; idx += 128)
    hs[idx >> 10][idx & (NH - 1)] = hlast[(bb + (idx >> 10)) * NH + (idx & (NH - 1))];
  __syncthreads();
  const int z = threadIdx.x;
  float am[4] = {0.f, 0.f, 0.f, 0.f};
  float av[4] = {0.f, 0.f, 0.f, 0.f};
#pragma unroll 8
  for (int k = 0; k < NH; ++k) {
    float wm = Wm[k * NZ + z];
    float wv = Wv[k * NZ + z];
#pragma unroll
    for (int r = 0; r < 4; ++r) {
      am[r] += hs[r][k] * wm;
      av[r] += hs[r][k] * wv;
    }
  }
#pragma unroll
  for (int r = 0; r < 4; ++r) {
    int b = bb + r;
    float mu = am[r] + bm[z];
    float lv = av[r] + bv[z];
    float zz = mu + eps[b * NZ + z] * expf(0.5f * lv);
    out[b * NZ + z] = mu;
    out[NB * NZ + b * NZ + z] = lv;
    out[2 * NB * NZ + b * NZ + z] = zz;
  }
}

// ---------------------------------------------------------------------------
extern "C" void kernel_launch(void* const* d_in, const int* in_sizes, int n_in,
                              void* d_out, int out_size, void* d_ws, size_t ws_size,
                              hipStream_t stream) {
  const float* x   = (const float*)d_in[0];
  const float* W   = (const float*)d_in[1];
  const float* U   = (const float*)d_in[2];
  const float* b   = (const float*)d_in[3];
  const float* Wm  = (const float*)d_in[4];
  const float* bm  = (const float*)d_in[5];
  const float* Wv  = (const float*)d_in[6];
  const float* bv  = (const float*)d_in[7];
  const float* eps = (const float*)d_in[8];

  // Workspace layout (needs ~34.6 MB):
  //   [0,       524288)   hbuf: 2 x B x H bf16
  //   [524288,  1048576)  hlast: B x H fp32
  //   [1048576, 1049600)  slots: 256 x u32 (padded to 4096)
  //   [1052672, +33.5MB)  xb: T x B x D bf16
  char* ws = (char*)d_ws;
  __bf16* hbuf = (__bf16*)ws;
  float* hlast = (float*)(ws + 524288);
  unsigned int* slots = (unsigned int*)(ws + 1048576);
  __bf16* xb = (__bf16*)(ws + 1048576 + 4096);

  hipMemsetAsync(hbuf, 0, NB * NH * sizeof(__bf16), stream);  // h_0 = 0
  hipMemsetAsync(slots, 0, 256 * sizeof(unsigned int), stream);

  convert_x_kernel<<<dim3((NB * NT * ND) / 4 / 256), dim3(256), 0, stream>>>(
      (const float4*)x, xb);

  void* args[] = {(void*)&xb, (void*)&W, (void*)&U, (void*)&b,
                  (void*)&hbuf, (void*)&hlast, (void*)&slots};
  hipLaunchCooperativeKernel(reinterpret_cast<void*>(lstm_persistent),
                             dim3(256), dim3(512), args, 0, stream);

  proj_kernel<<<dim3(32), dim3(128), 0, stream>>>(hlast, Wm, bm, Wv, bv, eps,
                                                  (float*)d_out);
}

// Round 5
// 4453.381 us; speedup vs baseline: 1.5023x; 1.5023x over previous
//
#include <hip/hip_runtime.h>
#include <hip/hip_bf16.h>
#include <stdint.h>

// Problem constants
#define NB 128    // batch
#define NT 512    // time steps
#define ND 256    // input dim
#define NH 1024   // hidden dim
#define NZ 128    // latent dim
#define NG 4096   // 4*NH gate width
#define NK 1280   // ND + NH combined K

typedef __attribute__((ext_vector_type(8))) __bf16 bf16x8;
typedef __attribute__((ext_vector_type(4))) __bf16 bf16x4;
typedef __attribute__((ext_vector_type(4))) float floatx4;

__device__ __forceinline__ float sigmoidf_(float x) { return 1.0f / (1.0f + expf(-x)); }
__device__ __forceinline__ float softplusf_(float x) {
  return (x > 0.0f) ? (x + log1pf(expf(-x))) : log1pf(expf(x));
}

// ---------------------------------------------------------------------------
// Kernel 1: convert x (B,T,D) fp32 -> xb (T,B,D) bf16
// ---------------------------------------------------------------------------
__global__ __launch_bounds__(256) void convert_x_kernel(
    const float4* __restrict__ x, __bf16* __restrict__ xb) {
  int i = blockIdx.x * 256 + threadIdx.x;   // [0, B*T*D/4)
  int d4 = i & 63;                          // float4 index within row of 256
  int bt = i >> 6;                          // b*512 + t
  int b = bt >> 9;
  int t = bt & 511;
  float4 v = x[i];
  bf16x4 o;
  o[0] = (__bf16)v.x; o[1] = (__bf16)v.y; o[2] = (__bf16)v.z; o[3] = (__bf16)v.w;
  *(bf16x4*)(xb + ((t * NB + b) * ND + d4 * 4)) = o;
}

// ---------------------------------------------------------------------------
// Kernel 2: persistent LSTM.
// ROUND-2 TILING (measured-best exchange shape) + ROUND-4 NAMED REGISTERS.
// Grid 256 WGs x 512 thr (1 WG/CU, cooperative). WG = (m_blk = blockIdx&7,
// n_blk = blockIdx>>3): batch rows [m_blk*16, +16), h-cols [n_blk*32, +32).
// Wave w: gate g = w>>1 (i,f,g,o), col-half = w&1 -> 16 gate cols, FULL
// K=1280: 40 named bf16x8 fragments (160 VGPRs). Round 2's Bf[40] array
// spilled (VGPR=116); round 4 proved named vars stay resident (VGPR=124).
// Round 4's m=32 reshape regressed (doubled LLC h-gather + 64-WG barrier
// groups): reverted here.
// Cross-WG h exchange + slot barrier: agent-scope atomics only (no fences,
// no L2 invalidation). x tile prefetched into regs before the barrier poll.
// ---------------------------------------------------------------------------
__global__ __launch_bounds__(512, 2) void lstm_persistent(
    const __bf16* __restrict__ xb,    // (T, B, D) bf16
    const float* __restrict__ W,      // (D, 4H)
    const float* __restrict__ U,      // (H, 4H)
    const float* __restrict__ bias,   // (4H)
    __bf16* __restrict__ hbuf,        // 2 * B * H bf16 (double buffer)
    float* __restrict__ hlast,        // B * H fp32
    unsigned int* __restrict__ slots) // 256 barrier slots (8 groups x 32)
{
  const int tid = threadIdx.x;
  const int wg = blockIdx.x;
  const int m_blk = wg & 7;
  const int n_blk = wg >> 3;
  const int wave = tid >> 6;
  const int lane = tid & 63;
  const int q = lane >> 4;     // k-quad
  const int n16 = lane & 15;   // MFMA col within 16-col tile
  const int g = wave >> 1;     // gate index 0..3 (i,f,g,o)
  const int half = wave & 1;   // which 16 of the 32 h-cols

  __shared__ __bf16 As[16 * 1288];  // A tile, rows padded 1280 -> 1288
  __shared__ float Gs[16][132];     // gates, padded 128 -> 132
  __shared__ __bf16 Hso[16][32];    // h output tile

  // ---- Load persistent B fragments as 40 NAMED bf16x8 (160 VGPRs) ----
  const int gc = g * NH + n_blk * 32 + half * 16 + n16;  // global gate column
#define LB(ii)                                                            \
  bf16x8 B##ii;                                                           \
  {                                                                       \
    const int k0 = (ii) * 32;                                             \
    const float* s = (k0 < 256) ? (W + k0 * NG + gc)                      \
                                : (U + (k0 - 256) * NG + gc);             \
    bf16x8 v;                                                             \
    v[0] = (__bf16)s[(q * 8 + 0) * NG]; v[1] = (__bf16)s[(q * 8 + 1) * NG]; \
    v[2] = (__bf16)s[(q * 8 + 2) * NG]; v[3] = (__bf16)s[(q * 8 + 3) * NG]; \
    v[4] = (__bf16)s[(q * 8 + 4) * NG]; v[5] = (__bf16)s[(q * 8 + 5) * NG]; \
    v[6] = (__bf16)s[(q * 8 + 6) * NG]; v[7] = (__bf16)s[(q * 8 + 7) * NG]; \
    B##ii = v;                                                            \
  }
  LB(0) LB(1) LB(2) LB(3) LB(4) LB(5) LB(6) LB(7) LB(8) LB(9)
  LB(10) LB(11) LB(12) LB(13) LB(14) LB(15) LB(16) LB(17) LB(18) LB(19)
  LB(20) LB(21) LB(22) LB(23) LB(24) LB(25) LB(26) LB(27) LB(28) LB(29)
  LB(30) LB(31) LB(32) LB(33) LB(34) LB(35) LB(36) LB(37) LB(38) LB(39)
#undef LB
  const float bgc = bias[gc];  // bias folded into accumulator init

  // ---- Elementwise-role constants: thread owns cell (r_e, c_e) ----
  const int r_e = tid >> 5;            // 0..15 row
  const int c_e = tid & 31;            // 0..31 h-col
  const int hcol = n_blk * 32 + c_e;   // [0, NH)
  const int grow = m_blk * 16 + r_e;   // [0, NB)
  float c_state = 0.0f;

  const int slot_base = m_blk * 32;

  // ---- Prefetch x tile for t=0 (16 rows x 256 = 512 16B chunks) ----
  bf16x8 xv = ((const bf16x8*)(xb + (m_blk * 16 + (tid >> 5)) * ND))[tid & 31];

  for (int t = 0; t < NT; ++t) {
    // ---- Stage A = [x_t | h_prev] (16 x 1280 bf16) into LDS ----
    {
      int r = tid >> 5, c = tid & 31;
      *(bf16x8*)(As + r * 1288 + c * 8) = xv;
      // h: agent-scope coherent 8B loads (LLC): 16 rows x 256 chunks
      const __bf16* hsrc = hbuf + (t & 1) * (NB * NH);
#pragma unroll
      for (int it = 0; it < 8; ++it) {
        int idx = tid + it * 512;
        int hr = idx >> 8, hc = idx & 255;
        unsigned long long v = __hip_atomic_load(
            (const unsigned long long*)(hsrc + (m_blk * 16 + hr) * NH) + hc,
            __ATOMIC_RELAXED, __HIP_MEMORY_SCOPE_AGENT);
        *(unsigned long long*)(As + hr * 1288 + 256 + hc * 4) = v;
      }
    }
    __syncthreads();

    // ---- MFMA: one 16x16 tile per wave, K=1280, two indep. acc chains ----
    floatx4 acc0 = {bgc, bgc, bgc, bgc};
    floatx4 acc1 = {0.f, 0.f, 0.f, 0.f};
    const __bf16* arow = As + n16 * 1288 + q * 8;
#define MF(ii, ACC)                                                        \
  {                                                                        \
    bf16x8 a = *(const bf16x8*)(arow + (ii) * 32);                         \
    ACC = __builtin_amdgcn_mfma_f32_16x16x32_bf16(a, B##ii, ACC, 0, 0, 0); \
  }
    MF(0, acc0) MF(1, acc1) MF(2, acc0) MF(3, acc1)
    MF(4, acc0) MF(5, acc1) MF(6, acc0) MF(7, acc1)
    MF(8, acc0) MF(9, acc1) MF(10, acc0) MF(11, acc1)
    MF(12, acc0) MF(13, acc1) MF(14, acc0) MF(15, acc1)
    MF(16, acc0) MF(17, acc1) MF(18, acc0) MF(19, acc1)
    MF(20, acc0) MF(21, acc1) MF(22, acc0) MF(23, acc1)
    MF(24, acc0) MF(25, acc1) MF(26, acc0) MF(27, acc1)
    MF(28, acc0) MF(29, acc1) MF(30, acc0) MF(31, acc1)
    MF(32, acc0) MF(33, acc1) MF(34, acc0) MF(35, acc1)
    MF(36, acc0) MF(37, acc1) MF(38, acc0) MF(39, acc1)
#undef MF
    floatx4 acc = acc0 + acc1;

    // ---- Spill gate tile to LDS: D[m=q*4+rr][n=n16] ----
    {
      int colL = g * 32 + half * 16 + n16;
#pragma unroll
      for (int rr = 0; rr < 4; ++rr) Gs[q * 4 + rr][colL] = acc[rr];
    }
    __syncthreads();  // gates ready (As fully consumed)

    // ---- LSTM cell (fp32, exact nonlinearities); bias already in gates ----
    {
      float xi = Gs[r_e][c_e];
      float xf = Gs[r_e][32 + c_e];
      float xg = Gs[r_e][64 + c_e];
      float xo = Gs[r_e][96 + c_e];
      float iv = sigmoidf_(xi);
      float fv = sigmoidf_(xf);
      float gv = softplusf_(xg);
      float ov = sigmoidf_(xo);
      c_state = fv * c_state + iv * gv;
      float hv = ov * softplusf_(c_state);
      Hso[r_e][c_e] = (__bf16)hv;
      if (t == NT - 1) hlast[grow * NH + hcol] = hv;
    }
    __syncthreads();  // Hso ready, Gs consumed

    if (t < NT - 1) {
      // ---- Prefetch next x tile (h-independent; completes during poll) ----
      xv = ((const bf16x8*)(xb + ((t + 1) * NB + m_blk * 16 + (tid >> 5)) * ND))[tid & 31];

      // ---- wave 0: publish h tile (16x32 bf16 = 128 x 8B, agent scope) ----
      if (tid < 64) {
        __bf16* hdst = hbuf + ((t + 1) & 1) * (NB * NH);
#pragma unroll
        for (int it = 0; it < 2; ++it) {
          int idx = tid + it * 64;          // 128 chunks of 8B
          int hr = idx >> 3, hc = idx & 7;  // row, 8B-chunk (32 cols = 8)
          unsigned long long v = *(const unsigned long long*)(&Hso[hr][hc * 4]);
          __hip_atomic_store(
              (unsigned long long*)(hdst + (m_blk * 16 + hr) * NH + n_blk * 32) + hc,
              v, __ATOMIC_RELAXED, __HIP_MEMORY_SCOPE_AGENT);
        }
      }
      if (tid == 0) {
        // release: same-wave h stores drain (vmcnt) before slot publish
        __hip_atomic_store(&slots[slot_base + n_blk], (unsigned)(t + 1),
                           __ATOMIC_RELEASE, __HIP_MEMORY_SCOPE_AGENT);
      }
      if (tid < 32) {  // wave 0 polls all 32 group slots
        unsigned tgt = (unsigned)(t + 1);
        while (__hip_atomic_load(&slots[slot_base + tid], __ATOMIC_RELAXED,
                                 __HIP_MEMORY_SCOPE_AGENT) < tgt) {
          __builtin_amdgcn_s_sleep(1);
        }
      }
      __syncthreads();  // all waves wait for barrier
    }
  }
}

// ---------------------------------------------------------------------------
// Kernel 3: projection head. 32 blocks x 128 thr; 4 batch rows per block.
// ---------------------------------------------------------------------------
__global__ __launch_bounds__(128) void proj_kernel(
    const float* __restrict__ hlast,
    const float* __restrict__ Wm, const float* __restrict__ bm,
    const float* __restrict__ Wv, const float* __restrict__ bv,
    const float* __restrict__ eps, float* __restrict__ out) {
  __shared__ float hs[4][NH];
  const int bb = blockIdx.x * 4;
  for (int idx = threadIdx.x; idx < 4 * NH; idx += 128)
    hs[idx >> 10][idx & (NH - 1)] = hlast[(bb + (idx >> 10)) * NH + (idx & (NH - 1))];
  __syncthreads();
  const int z = threadIdx.x;
  float am[4] = {0.f, 0.f, 0.f, 0.f};
  float av[4] = {0.f, 0.f, 0.f, 0.f};
#pragma unroll 8
  for (int k = 0; k < NH; ++k) {
    float wm = Wm[k * NZ + z];
    float wv = Wv[k * NZ + z];
#pragma unroll
    for (int r = 0; r < 4; ++r) {
      am[r] += hs[r][k] * wm;
      av[r] += hs[r][k] * wv;
    }
  }
#pragma unroll
  for (int r = 0; r < 4; ++r) {
    int b = bb + r;
    float mu = am[r] + bm[z];
    float lv = av[r] + bv[z];
    float zz = mu + eps[b * NZ + z] * expf(0.5f * lv);
    out[b * NZ + z] = mu;
    out[NB * NZ + b * NZ + z] = lv;
    out[2 * NB * NZ + b * NZ + z] = zz;
  }
}

// ---------------------------------------------------------------------------
extern "C" void kernel_launch(void* const* d_in, const int* in_sizes, int n_in,
                              void* d_out, int out_size, void* d_ws, size_t ws_size,
                              hipStream_t stream) {
  const float* x   = (const float*)d_in[0];
  const float* W   = (const float*)d_in[1];
  const float* U   = (const float*)d_in[2];
  const float* b   = (const float*)d_in[3];
  const float* Wm  = (const float*)d_in[4];
  const float* bm  = (const float*)d_in[5];
  const float* Wv  = (const float*)d_in[6];
  const float* bv  = (const float*)d_in[7];
  const float* eps = (const float*)d_in[8];

  // Workspace layout (needs ~34.6 MB):
  //   [0,       524288)   hbuf: 2 x B x H bf16
  //   [524288,  1048576)  hlast: B x H fp32
  //   [1048576, 1049600)  slots: 256 x u32 (padded to 4096)
  //   [1052672, +33.5MB)  xb: T x B x D bf16
  char* ws = (char*)d_ws;
  __bf16* hbuf = (__bf16*)ws;
  float* hlast = (float*)(ws + 524288);
  unsigned int* slots = (unsigned int*)(ws + 1048576);
  __bf16* xb = (__bf16*)(ws + 1048576 + 4096);

  hipMemsetAsync(hbuf, 0, NB * NH * sizeof(__bf16), stream);  // h_0 = 0
  hipMemsetAsync(slots, 0, 256 * sizeof(unsigned int), stream);

  convert_x_kernel<<<dim3((NB * NT * ND) / 4 / 256), dim3(256), 0, stream>>>(
      (const float4*)x, xb);

  void* args[] = {(void*)&xb, (void*)&W, (void*)&U, (void*)&b,
                  (void*)&hbuf, (void*)&hlast, (void*)&slots};
  hipLaunchCooperativeKernel(reinterpret_cast<void*>(lstm_persistent),
                             dim3(256), dim3(512), args, 0, stream);

  proj_kernel<<<dim3(32), dim3(128), 0, stream>>>(hlast, Wm, bm, Wv, bv, eps,
                                                  (float*)d_out);
}